// Round 14
// baseline (93.419 us; speedup 1.0000x reference)
//
#include <hip/hip_runtime.h>
#include <hip/hip_bf16.h>

#define NH    12
#define HD    64
#define NTOK  1024
#define BATCH 8
#define DM    768

typedef short  short8  __attribute__((ext_vector_type(8)));
typedef float  f32x4   __attribute__((ext_vector_type(4)));
typedef float  f32x16  __attribute__((ext_vector_type(16)));
typedef unsigned short ushort8 __attribute__((ext_vector_type(8)));

// sqrt(0.125 * log2(e)) — pre-scales vn so QK^T yields CS*cos directly
#define SQRT_CS 0.42466056f

__device__ __forceinline__ ushort f2bf(float f) {
    union { float f; unsigned u; } x; x.f = f;
    unsigned r = x.u + 0x7FFF + ((x.u >> 16) & 1);   // RNE
    return (ushort)(r >> 16);
}
__device__ __forceinline__ float bf2f(ushort h) {
    union { unsigned u; float f; } x; x.u = ((unsigned)h) << 16;
    return x.f;
}
__device__ __forceinline__ void gl_lds16(const ushort* g, ushort* l) {
    __builtin_amdgcn_global_load_lds(
        (const __attribute__((address_space(1))) unsigned int*)g,
        (__attribute__((address_space(3))) unsigned int*)l, 16, 0, 0);
}
__device__ __forceinline__ f32x16 mfma32(short8 a, short8 b, f32x16 c) {
    return __builtin_amdgcn_mfma_f32_32x32x16_bf16(a, b, c, 0, 0, 0);
}

// ---------------------------------------------------------------------------
// Merged split kernel: x -> (hi, lo) bf16, for q (with [n][b][d]->[b][n][d]
// transpose) and w, in one launch.
// ---------------------------------------------------------------------------
__global__ __launch_bounds__(256) void split_qw_kernel(
    const float* __restrict__ qsrc, const float* __restrict__ wsrc,
    ushort* __restrict__ qhi, ushort* __restrict__ qlo,
    ushort* __restrict__ whi, ushort* __restrict__ wlo)
{
    const int NQ = (NTOK * BATCH * DM) / 8;       // 786432
    int t = blockIdx.x * 256 + threadIdx.x;
    const float* s;
    ushort *dh, *dl;
    size_t o;
    if (t < NQ) {
        int dblk = t % 96; int nb = t / 96; int b = nb & 7; int n = nb >> 3;
        s = qsrc + (size_t)t * 8;
        o = ((size_t)(b * 1024 + n) * 96 + dblk) * 8;
        dh = qhi; dl = qlo;
    } else {
        int tw = t - NQ;
        if (tw >= (DM * DM) / 8) return;
        s = wsrc + (size_t)tw * 8;
        o = (size_t)tw * 8;
        dh = whi; dl = wlo;
    }
    float4 x0 = *(const float4*)s, x1 = *(const float4*)(s + 4);
    float xs[8] = {x0.x, x0.y, x0.z, x0.w, x1.x, x1.y, x1.z, x1.w};
    ushort8 h8, l8;
    #pragma unroll
    for (int j = 0; j < 8; ++j) {
        ushort h = f2bf(xs[j]);
        h8[j] = h;
        l8[j] = f2bf(xs[j] - bf2f(h));
    }
    *(ushort8*)(dh + o) = h8;
    *(ushort8*)(dl + o) = l8;
}

// ---------------------------------------------------------------------------
// vproj via split-bf16 MFMA: C = Ah.Bh + Ah.Bl + Al.Bh  (fp32 accum).
// 128x64 tile (ONE head per block), BK=64, 4 waves of 32 rows x 64 cols,
// 32x32x16 MFMA. Grid 768 = 3 blocks/CU (vs 384 = 1.5 before): barrier
// drains overlap across 3 independent blocks. LDS 48 KB (3 blocks fit).
// XCD decode: 8 row-panels x 12 heads per XCD -> A hi/lo (3.1 MB) pinned.
// Epilogue: Ct [128][68] f32 bounce -> per-row norm -> vn (xSQRT_CS) + vt.
// ---------------------------------------------------------------------------
__global__ __launch_bounds__(256) void vproj_mfma_kernel(
    const ushort* __restrict__ qh, const ushort* __restrict__ ql,
    const ushort* __restrict__ wh, const ushort* __restrict__ wl,
    ushort* __restrict__ vn, ushort* __restrict__ vt)
{
    __shared__ __align__(16) char smem[49152];   // 48 KB
    ushort* Ah = (ushort*)smem;                  // [128][64] chunk-swizzled
    ushort* Al = (ushort*)(smem + 16384);
    ushort* Bh = (ushort*)(smem + 32768);        // [64][64]
    ushort* Bl = (ushort*)(smem + 40960);

    const int bid = blockIdx.x;                  // 0..767
    const int xcd = bid & 7, idx = bid >> 3;     // idx 0..95
    const int mbl = idx & 7, hh = idx >> 3;      // hh 0..11 (head)
    const int mb  = xcd * 8 + mbl;               // 0..63 row-panel
    const int m0  = mb * 128;
    const int n0  = hh * 64;

    const int tid = threadIdx.x, wv = tid >> 6, l = tid & 63;
    const int ln  = l & 31, half = l >> 5;

    const ushort* gsrc = (wv == 0) ? qh : (wv == 1) ? ql : (wv == 2) ? wh : wl;
    ushort* ltile = (wv == 0) ? Ah : (wv == 1) ? Al : (wv == 2) ? Bh : Bl;
    const int srow0 = (wv < 2) ? m0 : n0;

    f32x16 acc[2] = {};

    for (int kt = 0; kt < 12; ++kt) {
        __syncthreads();                          // prev ds_reads done
        if (wv < 2) {                             // A: 128 rows = 16 chunks/lane
            #pragma unroll
            for (int p = 0; p < 16; ++p) {
                int chunk = p * 64 + l;
                int r = chunk >> 3, c = chunk & 7;
                int csrc = c ^ (r & 7);           // inverse-swizzled source
                gl_lds16(gsrc + (size_t)(srow0 + r) * 768 + kt * 64 + csrc * 8,
                         ltile + p * 512);
            }
        } else {                                  // B: 64 rows = 8 chunks/lane
            #pragma unroll
            for (int p = 0; p < 8; ++p) {
                int chunk = p * 64 + l;
                int r = chunk >> 3, c = chunk & 7;
                int csrc = c ^ (r & 7);
                gl_lds16(gsrc + (size_t)(srow0 + r) * 768 + kt * 64 + csrc * 8,
                         ltile + p * 512);
            }
        }
        __syncthreads();                          // vmcnt(0) drained here

        #pragma unroll
        for (int ks = 0; ks < 4; ++ks) {
            const int cc = ks * 2 + half;         // k-chunk: k = cc*8 + j
            const int ra = wv * 32 + ln;
            const int sa = (cc ^ (ra & 7)) * 8;
            short8 a_h = *(const short8*)(Ah + ra * 64 + sa);
            short8 a_l = *(const short8*)(Al + ra * 64 + sa);
            short8 b_h[2], b_l[2];
            #pragma unroll
            for (int ni = 0; ni < 2; ++ni) {
                int rb = ni * 32 + ln;
                int sb = (cc ^ (rb & 7)) * 8;
                b_h[ni] = *(const short8*)(Bh + rb * 64 + sb);
                b_l[ni] = *(const short8*)(Bl + rb * 64 + sb);
            }
            #pragma unroll
            for (int ni = 0; ni < 2; ++ni) {
                acc[ni] = mfma32(a_h, b_h[ni], acc[ni]);
                acc[ni] = mfma32(a_h, b_l[ni], acc[ni]);
                acc[ni] = mfma32(a_l, b_h[ni], acc[ni]);
            }
        }
    }

    // ---- epilogue: C tile -> LDS [128][68] f32, norms, vn + vt ----
    __syncthreads();
    float* Ct = (float*)smem;                     // 128*68*4 = 34816 B
    #pragma unroll
    for (int ni = 0; ni < 2; ++ni)
        #pragma unroll
        for (int i = 0; i < 16; ++i) {
            int row = wv * 32 + (i & 3) + 8 * (i >> 2) + 4 * half;
            Ct[row * 68 + ni * 32 + ln] = acc[ni][i];
        }
    __syncthreads();

    const int b   = mb >> 3;
    const int nr0 = (mb & 7) * 128;
    const int bhn = b * NH + hh;
    {   // vn: thread t -> row t>>1, 32-col part t&1 (pair-reduce via shfl)
        int r = tid >> 1, part = tid & 1;
        const float* src = Ct + r * 68 + part * 32;
        float ss = 0.f;
        #pragma unroll
        for (int j = 0; j < 8; ++j) {
            float4 v4 = *(const float4*)(src + j * 4);
            ss += v4.x * v4.x + v4.y * v4.y + v4.z * v4.z + v4.w * v4.w;
        }
        ss += __shfl_xor(ss, 1);
        float rn = rsqrtf(ss) * SQRT_CS;          // fold softmax scale into vn
        ushort* dst = vn + ((size_t)bhn * NTOK + nr0 + r) * HD + part * 32;
        #pragma unroll
        for (int q8 = 0; q8 < 4; ++q8) {
            float4 u0 = *(const float4*)(src + q8 * 8);
            float4 u1 = *(const float4*)(src + q8 * 8 + 4);
            ushort8 o;
            o[0] = f2bf(u0.x * rn); o[1] = f2bf(u0.y * rn);
            o[2] = f2bf(u0.z * rn); o[3] = f2bf(u0.w * rn);
            o[4] = f2bf(u1.x * rn); o[5] = f2bf(u1.y * rn);
            o[6] = f2bf(u1.z * rn); o[7] = f2bf(u1.w * rn);
            *(ushort8*)(dst + q8 * 8) = o;
        }
    }
    {   // vt: thread t -> col d = t&63, 32-row segment seg = t>>6
        int d = tid & 63, seg = tid >> 6;
        ushort* dst = vt + ((size_t)bhn * HD + d) * NTOK + nr0 + seg * 32;
        #pragma unroll
        for (int q8 = 0; q8 < 4; ++q8) {
            ushort8 o;
            #pragma unroll
            for (int j = 0; j < 8; ++j)
                o[j] = f2bf(Ct[(seg * 32 + q8 * 8 + j) * 68 + d]);
            *(ushort8*)(dst + q8 * 8) = o;
        }
    }
}

// ---------------------------------------------------------------------------
// Fallback fp32 vproj (used only if ws_size can't hold the split arrays).
// ---------------------------------------------------------------------------
__global__ __launch_bounds__(256) void vproj_fp32_kernel(
    const float* __restrict__ q, const float* __restrict__ w,
    ushort* __restrict__ vn, ushort* __restrict__ vt)
{
    __shared__ __align__(16) char smem[2 * 32 * 65 * 4];
    float (*As)[65] = (float (*)[65])smem;
    float (*Bs)[65] = (float (*)[65])(smem + 32 * 65 * 4);
    const int h = blockIdx.x, mb = blockIdx.y;
    const int tid = threadIdx.x;
    const int tx = tid & 15, ty = tid >> 4;
    const int m0 = mb * 64, b = m0 >> 10;
    const int lk = tid & 31, lr = tid >> 5;
    float acc[4][4] = {};
    for (int kt = 0; kt < DM; kt += 32) {
        #pragma unroll
        for (int p = 0; p < 8; ++p) {
            int row = lr + p * 8;
            int n = (m0 + row) & (NTOK - 1);
            As[lk][row] = q[(size_t)(n * BATCH + b) * DM + kt + lk];
            Bs[lk][row] = w[(size_t)(h * HD + row) * DM + kt + lk];
        }
        __syncthreads();
        #pragma unroll 8
        for (int k = 0; k < 32; ++k) {
            float a0 = As[k][4*ty+0], a1 = As[k][4*ty+1];
            float a2 = As[k][4*ty+2], a3 = As[k][4*ty+3];
            float b0 = Bs[k][4*tx+0], b1 = Bs[k][4*tx+1];
            float b2 = Bs[k][4*tx+2], b3 = Bs[k][4*tx+3];
            acc[0][0]+=a0*b0; acc[0][1]+=a0*b1; acc[0][2]+=a0*b2; acc[0][3]+=a0*b3;
            acc[1][0]+=a1*b0; acc[1][1]+=a1*b1; acc[1][2]+=a1*b2; acc[1][3]+=a1*b3;
            acc[2][0]+=a2*b0; acc[2][1]+=a2*b1; acc[2][2]+=a2*b2; acc[2][3]+=a2*b3;
            acc[3][0]+=a3*b0; acc[3][1]+=a3*b1; acc[3][2]+=a3*b2; acc[3][3]+=a3*b3;
        }
        __syncthreads();
    }
    const int bh = b * NH + h;
    const int n0 = m0 & (NTOK - 1);
    #pragma unroll
    for (int i = 0; i < 4; ++i) {
        float ss = acc[i][0]*acc[i][0] + acc[i][1]*acc[i][1]
                 + acc[i][2]*acc[i][2] + acc[i][3]*acc[i][3];
        #pragma unroll
        for (int msk = 1; msk < 16; msk <<= 1) ss += __shfl_xor(ss, msk, 16);
        float rn = rsqrtf(ss) * SQRT_CS;
        int n = n0 + 4*ty + i;
        ushort4 o;
        o.x = f2bf(acc[i][0]*rn); o.y = f2bf(acc[i][1]*rn);
        o.z = f2bf(acc[i][2]*rn); o.w = f2bf(acc[i][3]*rn);
        *(ushort4*)&vn[((size_t)bh * NTOK + n) * HD + 4*tx] = o;
    }
    ushort (*T)[72] = (ushort (*)[72])smem;
    #pragma unroll
    for (int i = 0; i < 4; ++i)
        #pragma unroll
        for (int j = 0; j < 4; ++j)
            T[4*tx + j][4*ty + i] = f2bf(acc[i][j]);
    __syncthreads();
    {
        int d = tid >> 2, c = tid & 3;
        uint4 lo = *(const uint4*)&T[d][c*16];
        uint4 hi = *(const uint4*)&T[d][c*16 + 8];
        size_t go = ((size_t)bh * HD + d) * NTOK + n0 + c*16;
        *(uint4*)&vt[go]     = lo;
        *(uint4*)&vt[go + 8] = hi;
    }
}

// ---------------------------------------------------------------------------
// Kernel 2: flash attention, round-12 group-pipelined version (unchanged).
// ---------------------------------------------------------------------------
__global__ __launch_bounds__(256) void attn_kernel(
    const ushort* __restrict__ vn, const ushort* __restrict__ vt,
    float* __restrict__ out)
{
    __shared__ __align__(16) ushort Klds[2][64 * 64];   // [kv][d], swizzled
    __shared__ __align__(16) ushort Vlds[2][64 * 64];   // [d][kv], swizzled
    const int sblk = blockIdx.x;                 // 0..767
    const int tt   = sblk >> 3;
    const int bh   = (sblk & 7) + 8 * (tt >> 3); // XCD(bid%8) == bh%8
    const int q0   = (tt & 7) * 128;
    const int tid = threadIdx.x;
    const int wv  = tid >> 6;
    const int l   = tid & 63;
    const int ql  = l & 31;          // q column (one q-row per lane)
    const int h   = l >> 5;          // half

    const ushort* vb  = vn + (size_t)bh * NTOK * HD;
    const ushort* vtb = vt + (size_t)bh * HD * NTOK;

    short8 qB[4];
    {
        int qrow = q0 + wv * 32 + ql;
        #pragma unroll
        for (int ks = 0; ks < 4; ++ks)
            qB[ks] = *(const short8*)(vb + (size_t)qrow * HD + ks * 16 + h * 8);
    }

    const int sr0 = tid >> 3, sr1 = sr0 + 32;
    const int sc  = tid & 7;
    const int slt = (sc ^ (sr0 & 7)) * 8;        // sr1&7 == sr0&7
    uint4 kreg0, kreg1, vreg0, vreg1;

    f32x16 oT[2] = {};
    float l_acc = 0.f;

    kreg0 = *(const uint4*)(vb + (size_t)sr0 * HD + sc * 8);
    kreg1 = *(const uint4*)(vb + (size_t)sr1 * HD + sc * 8);
    vreg0 = *(const uint4*)(vtb + (size_t)sr0 * NTOK + sc * 8);
    vreg1 = *(const uint4*)(vtb + (size_t)sr1 * NTOK + sc * 8);
    *(uint4*)(&Klds[0][0] + sr0 * 64 + slt) = kreg0;
    *(uint4*)(&Klds[0][0] + sr1 * 64 + slt) = kreg1;
    *(uint4*)(&Vlds[0][0] + sr0 * 64 + slt) = vreg0;
    *(uint4*)(&Vlds[0][0] + sr1 * 64 + slt) = vreg1;
    __syncthreads();

    for (int kt = 0; kt < NTOK / 64; ++kt) {
        const int cur = kt & 1;
        const ushort* Kb = &Klds[cur][0];
        const ushort* Vb = &Vlds[cur][0];

        // T14: issue next tile's global loads early (land during compute)
        if (kt < NTOK / 64 - 1) {
            int kb = (kt + 1) * 64;
            kreg0 = *(const uint4*)(vb + (size_t)(kb + sr0) * HD + sc * 8);
            kreg1 = *(const uint4*)(vb + (size_t)(kb + sr1) * HD + sc * 8);
            vreg0 = *(const uint4*)(vtb + (size_t)sr0 * NTOK + kb + sc * 8);
            vreg1 = *(const uint4*)(vtb + (size_t)sr1 * NTOK + kb + sc * 8);
        }

        // QK^T: both 32-kv groups (chains interleave freely)
        f32x16 st[2] = {};
        #pragma unroll
        for (int ks = 0; ks < 4; ++ks) {
            int so = ((2 * ks + h) ^ (ql & 7)) * 8;
            short8 k0 = *(const short8*)(Kb + ql * 64 + so);
            short8 k1 = *(const short8*)(Kb + (32 + ql) * 64 + so);
            st[0] = mfma32(k0, qB[ks], st[0]);
            st[1] = mfma32(k1, qB[ks], st[1]);
        }

        // per group: exp2 -> sum -> pack -> PV  (group 1's VALU overlaps
        // group 0's PV MFMAs; no setprio fences)
        #pragma unroll
        for (int g = 0; g < 2; ++g) {
            #pragma unroll
            for (int i = 0; i < 16; ++i)
                st[g][i] = __builtin_amdgcn_exp2f(st[g][i]);

            float ts[8];
            #pragma unroll
            for (int i = 0; i < 8; ++i) ts[i] = st[g][i] + st[g][i + 8];
            #pragma unroll
            for (int s = 4; s >= 1; s >>= 1)
                #pragma unroll
                for (int i = 0; i < s; ++i) ts[i] += ts[i + s];
            l_acc += ts[0];

            unsigned pb2[4][2];
            #pragma unroll
            for (int t = 0; t < 4; ++t)
                #pragma unroll
                for (int u = 0; u < 2; ++u)
                    asm("v_cvt_pk_bf16_f32 %0, %1, %2"
                        : "=v"(pb2[t][u])
                        : "v"(st[g][4 * t + 2 * u]), "v"(st[g][4 * t + 2 * u + 1]));

            #pragma unroll
            for (int sp = 0; sp < 2; ++sp) {
                const int s = g * 2 + sp;
                unsigned x0 = pb2[2 * sp][0], y0 = pb2[2 * sp + 1][0];
                unsigned x1 = pb2[2 * sp][1], y1 = pb2[2 * sp + 1][1];
                asm volatile("v_permlane32_swap_b32 %0, %1" : "+v"(x0), "+v"(y0));
                asm volatile("v_permlane32_swap_b32 %0, %1" : "+v"(x1), "+v"(y1));
                union { unsigned u[4]; short8 s8; } pb;
                pb.u[0] = x0; pb.u[1] = x1; pb.u[2] = y0; pb.u[3] = y1;
                int so = ((2 * s + h) ^ (ql & 7)) * 8;
                short8 v0 = *(const short8*)(Vb + ql * 64 + so);
                short8 v1 = *(const short8*)(Vb + (32 + ql) * 64 + so);
                oT[0] = mfma32(v0, pb.s8, oT[0]);
                oT[1] = mfma32(v1, pb.s8, oT[1]);
            }
        }

        __syncthreads();                 // all waves done reading tile kt
        if (kt < NTOK / 64 - 1) {
            *(uint4*)(&Klds[cur ^ 1][0] + sr0 * 64 + slt) = kreg0;
            *(uint4*)(&Klds[cur ^ 1][0] + sr1 * 64 + slt) = kreg1;
            *(uint4*)(&Vlds[cur ^ 1][0] + sr0 * 64 + slt) = vreg0;
            *(uint4*)(&Vlds[cur ^ 1][0] + sr1 * 64 + slt) = vreg1;
            __syncthreads();
        }
    }

    const int b = bh / NH, hh = bh % NH;
    float lsum = l_acc + __shfl_xor(l_acc, 32);
    const float inv = 1.f / lsum;
    int n = q0 + wv * 32 + ql;
    float* orow = out + ((size_t)n * BATCH + b) * DM + hh * HD;
    #pragma unroll
    for (int dm = 0; dm < 2; ++dm)
        #pragma unroll
        for (int t = 0; t < 4; ++t) {
            float4 val = make_float4(oT[dm][4 * t] * inv, oT[dm][4 * t + 1] * inv,
                                     oT[dm][4 * t + 2] * inv, oT[dm][4 * t + 3] * inv);
            *(float4*)(orow + dm * 32 + t * 8 + h * 4) = val;
        }
}

extern "C" void kernel_launch(void* const* d_in, const int* in_sizes, int n_in,
                              void* d_out, int out_size, void* d_ws, size_t ws_size,
                              hipStream_t stream) {
    const float* q = (const float*)d_in[0];   // [1024, 8, 768]
    const float* w = (const float*)d_in[1];   // [768, 768]
    float* out = (float*)d_out;               // [1024, 8, 768]

    const size_t QE = (size_t)NTOK * BATCH * DM;     // 6,291,456
    const size_t WE = (size_t)DM * DM;               //   589,824
    const size_t VE = (size_t)NH * BATCH * NTOK * HD;// 6,291,456

    ushort* vn = (ushort*)d_ws;
    ushort* vt = vn + VE;
    size_t need = (2 * VE + 2 * QE + 2 * WE) * sizeof(ushort);

    if (ws_size >= need) {
        ushort* qh = vt + VE;
        ushort* ql = qh + QE;
        ushort* wh = ql + QE;
        ushort* wl = wh + WE;
        int nsplit = (int)((QE / 8 + WE / 8 + 255) / 256);
        split_qw_kernel<<<nsplit, 256, 0, stream>>>(q, w, qh, ql, wh, wl);
        vproj_mfma_kernel<<<768, 256, 0, stream>>>(qh, ql, wh, wl, vn, vt);
    } else {
        vproj_fp32_kernel<<<dim3(NH, (BATCH * NTOK) / 64), 256, 0, stream>>>(q, w, vn, vt);
    }
    attn_kernel<<<NTOK / 128 * BATCH * NH, 256, 0, stream>>>(vn, vt, out);
}

// Round 16
// 90.516 us; speedup vs baseline: 1.0321x; 1.0321x over previous
//
#include <hip/hip_runtime.h>
#include <hip/hip_bf16.h>

#define NH    12
#define HD    64
#define NTOK  1024
#define BATCH 8
#define DM    768

typedef short  short8  __attribute__((ext_vector_type(8)));
typedef float  f32x4   __attribute__((ext_vector_type(4)));
typedef float  f32x16  __attribute__((ext_vector_type(16)));
typedef unsigned short ushort8 __attribute__((ext_vector_type(8)));

// sqrt(0.125 * log2(e)) — pre-scales vn so QK^T yields CS*cos directly
#define SQRT_CS 0.42466056f

__device__ __forceinline__ ushort f2bf(float f) {
    union { float f; unsigned u; } x; x.f = f;
    unsigned r = x.u + 0x7FFF + ((x.u >> 16) & 1);   // RNE
    return (ushort)(r >> 16);
}
__device__ __forceinline__ void gl_lds16f(const float* g, char* l) {
    __builtin_amdgcn_global_load_lds(
        (const __attribute__((address_space(1))) unsigned int*)g,
        (__attribute__((address_space(3))) unsigned int*)l, 16, 0, 0);
}
__device__ __forceinline__ f32x16 mfma32(short8 a, short8 b, f32x16 c) {
    return __builtin_amdgcn_mfma_f32_32x32x16_bf16(a, b, c, 0, 0, 0);
}

// in-register split: 8 fp32 (two uint4) -> hi bf16x8 + lo bf16x8 (RNE, bit-
// identical to the former split kernels: hi = bf16(x), lo = bf16(x - hi)).
__device__ __forceinline__ void split8(uint4 c0, uint4 c1,
                                       short8& hi8, short8& lo8) {
    const unsigned xs[8] = {c0.x, c0.y, c0.z, c0.w, c1.x, c1.y, c1.z, c1.w};
    union { unsigned u[4]; short8 s; } H, L;
    #pragma unroll
    for (int j = 0; j < 4; ++j) {
        float a0 = __uint_as_float(xs[2 * j]);
        float a1 = __uint_as_float(xs[2 * j + 1]);
        unsigned hp;
        asm("v_cvt_pk_bf16_f32 %0, %1, %2" : "=v"(hp) : "v"(a0), "v"(a1));
        float l0 = a0 - __uint_as_float(hp << 16);
        float l1 = a1 - __uint_as_float(hp & 0xFFFF0000u);
        unsigned lp;
        asm("v_cvt_pk_bf16_f32 %0, %1, %2" : "=v"(lp) : "v"(l0), "v"(l1));
        H.u[j] = hp; L.u[j] = lp;
    }
    hi8 = H.s; lo8 = L.s;
}

// ---------------------------------------------------------------------------
// vproj: v = q @ w^T via split-bf16 MFMA (C = Ah.Bh + Ah.Bl + Al.Bh, fp32
// accum), splitting done IN-REGISTER from fp32-staged tiles (bf16 hi+lo =
// 4B/elem = fp32, so LDS bytes / load counts are identical to the old
// pre-split path — the split kernels are eliminated entirely).
// 128x64 tile (one head), BK=64, 4 waves of 32 rows. fp32 rows stored as
// TWO 128B-row subtiles (even/odd k-half) with the same ^(r&7) chunk
// swizzle as before -> same conflict behavior. q read directly (no
// transpose: gather rows (n*8+b) per-lane). Grid 768, XCD-pinned.
// Epilogue: Ct [128][68] f32 bounce -> row norm -> vn (xSQRT_CS) + vt.
// ---------------------------------------------------------------------------
__global__ __launch_bounds__(256) void vproj_mfma_kernel(
    const float* __restrict__ qf, const float* __restrict__ wf,
    ushort* __restrict__ vn, ushort* __restrict__ vt)
{
    __shared__ __align__(16) char smem[49152];   // 48 KB
    char* Ae = smem;                // A k-half [0,32): [128][128B] swizzled
    char* Ao = smem + 16384;        // A k-half [32,64)
    char* Be = smem + 32768;        // B k-half [0,32): [64][128B]
    char* Bo = smem + 40960;        // B k-half [32,64)

    const int bid = blockIdx.x;                  // 0..767
    const int xcd = bid & 7, idx = bid >> 3;     // idx 0..95
    const int mbl = idx & 7, hh = idx >> 3;      // hh 0..11 (head)
    const int mb  = xcd * 8 + mbl;               // 0..63 row-panel
    const int b   = mb >> 3;
    const int nr0 = (mb & 7) * 128;
    const int n0  = hh * 64;

    const int tid = threadIdx.x, wv = tid >> 6, l = tid & 63;
    const int ln  = l & 31, half = l >> 5;

    f32x16 acc[2] = {};

    for (int kt = 0; kt < 12; ++kt) {
        __syncthreads();                          // prev ds_reads done
        if (wv < 2) {                             // A: fp32, 16 instr/wave
            char* dstT = wv ? Ao : Ae;
            const int kofs = kt * 64 + wv * 32;
            #pragma unroll
            for (int p = 0; p < 16; ++p) {
                int chunk = p * 64 + l;
                int r = chunk >> 3, c = chunk & 7;
                int csrc = c ^ (r & 7);           // inverse-swizzled source
                gl_lds16f(qf + ((size_t)((nr0 + r) * 8 + b)) * 768 + kofs + csrc * 4,
                          dstT + p * 1024);
            }
        } else {                                  // B: fp32, 8 instr/wave
            char* dstT = (wv == 3) ? Bo : Be;
            const int kofs = kt * 64 + (wv == 3 ? 32 : 0);
            #pragma unroll
            for (int p = 0; p < 8; ++p) {
                int chunk = p * 64 + l;
                int r = chunk >> 3, c = chunk & 7;
                int csrc = c ^ (r & 7);
                gl_lds16f(wf + (size_t)(n0 + r) * 768 + kofs + csrc * 4,
                          dstT + p * 1024);
            }
        }
        __syncthreads();                          // vmcnt(0) drained here

        #pragma unroll
        for (int ks = 0; ks < 4; ++ks) {
            const int cc  = ks * 2 + half;        // bf16 k-chunk 0..7
            const int cc2 = (cc & 3) * 2;         // fp32 16B-chunk pair base
            const int ra  = wv * 32 + ln;
            const char* At = (cc < 4) ? Ae : Ao;
            uint4 a0 = *(const uint4*)(At + ra * 128 + ((cc2 ^ (ra & 7)) * 16));
            uint4 a1 = *(const uint4*)(At + ra * 128 + (((cc2 + 1) ^ (ra & 7)) * 16));
            short8 a_h, a_l;
            split8(a0, a1, a_h, a_l);
            short8 b_h[2], b_l[2];
            const char* Bt = (cc < 4) ? Be : Bo;
            #pragma unroll
            for (int ni = 0; ni < 2; ++ni) {
                int rb = ni * 32 + ln;
                uint4 b0 = *(const uint4*)(Bt + rb * 128 + ((cc2 ^ (rb & 7)) * 16));
                uint4 b1 = *(const uint4*)(Bt + rb * 128 + (((cc2 + 1) ^ (rb & 7)) * 16));
                split8(b0, b1, b_h[ni], b_l[ni]);
            }
            #pragma unroll
            for (int ni = 0; ni < 2; ++ni) {
                acc[ni] = mfma32(a_h, b_h[ni], acc[ni]);
                acc[ni] = mfma32(a_h, b_l[ni], acc[ni]);
                acc[ni] = mfma32(a_l, b_h[ni], acc[ni]);
            }
        }
    }

    // ---- epilogue: C tile -> LDS [128][68] f32, norms, vn + vt ----
    __syncthreads();
    float* Ct = (float*)smem;                     // 128*68*4 = 34816 B
    #pragma unroll
    for (int ni = 0; ni < 2; ++ni)
        #pragma unroll
        for (int i = 0; i < 16; ++i) {
            int row = wv * 32 + (i & 3) + 8 * (i >> 2) + 4 * half;
            Ct[row * 68 + ni * 32 + ln] = acc[ni][i];
        }
    __syncthreads();

    const int bhn = b * NH + hh;
    {   // vn: thread t -> row t>>1, 32-col part t&1 (pair-reduce via shfl)
        int r = tid >> 1, part = tid & 1;
        const float* src = Ct + r * 68 + part * 32;
        float ss = 0.f;
        #pragma unroll
        for (int j = 0; j < 8; ++j) {
            float4 v4 = *(const float4*)(src + j * 4);
            ss += v4.x * v4.x + v4.y * v4.y + v4.z * v4.z + v4.w * v4.w;
        }
        ss += __shfl_xor(ss, 1);
        float rn = rsqrtf(ss) * SQRT_CS;          // fold softmax scale into vn
        ushort* dst = vn + ((size_t)bhn * NTOK + nr0 + r) * HD + part * 32;
        #pragma unroll
        for (int q8 = 0; q8 < 4; ++q8) {
            float4 u0 = *(const float4*)(src + q8 * 8);
            float4 u1 = *(const float4*)(src + q8 * 8 + 4);
            ushort8 o;
            o[0] = f2bf(u0.x * rn); o[1] = f2bf(u0.y * rn);
            o[2] = f2bf(u0.z * rn); o[3] = f2bf(u0.w * rn);
            o[4] = f2bf(u1.x * rn); o[5] = f2bf(u1.y * rn);
            o[6] = f2bf(u1.z * rn); o[7] = f2bf(u1.w * rn);
            *(ushort8*)(dst + q8 * 8) = o;
        }
    }
    {   // vt: thread t -> col d = t&63, 32-row segment seg = t>>6
        int d = tid & 63, seg = tid >> 6;
        ushort* dst = vt + ((size_t)bhn * HD + d) * NTOK + nr0 + seg * 32;
        #pragma unroll
        for (int q8 = 0; q8 < 4; ++q8) {
            ushort8 o;
            #pragma unroll
            for (int j = 0; j < 8; ++j)
                o[j] = f2bf(Ct[(seg * 32 + q8 * 8 + j) * 68 + d]);
            *(ushort8*)(dst + q8 * 8) = o;
        }
    }
}

// ---------------------------------------------------------------------------
// Kernel 2: flash attention, round-12 group-pipelined version (unchanged).
// ---------------------------------------------------------------------------
__global__ __launch_bounds__(256) void attn_kernel(
    const ushort* __restrict__ vn, const ushort* __restrict__ vt,
    float* __restrict__ out)
{
    __shared__ __align__(16) ushort Klds[2][64 * 64];   // [kv][d], swizzled
    __shared__ __align__(16) ushort Vlds[2][64 * 64];   // [d][kv], swizzled
    const int sblk = blockIdx.x;                 // 0..767
    const int tt   = sblk >> 3;
    const int bh   = (sblk & 7) + 8 * (tt >> 3); // XCD(bid%8) == bh%8
    const int q0   = (tt & 7) * 128;
    const int tid = threadIdx.x;
    const int wv  = tid >> 6;
    const int l   = tid & 63;
    const int ql  = l & 31;          // q column (one q-row per lane)
    const int h   = l >> 5;          // half

    const ushort* vb  = vn + (size_t)bh * NTOK * HD;
    const ushort* vtb = vt + (size_t)bh * HD * NTOK;

    short8 qB[4];
    {
        int qrow = q0 + wv * 32 + ql;
        #pragma unroll
        for (int ks = 0; ks < 4; ++ks)
            qB[ks] = *(const short8*)(vb + (size_t)qrow * HD + ks * 16 + h * 8);
    }

    const int sr0 = tid >> 3, sr1 = sr0 + 32;
    const int sc  = tid & 7;
    const int slt = (sc ^ (sr0 & 7)) * 8;        // sr1&7 == sr0&7
    uint4 kreg0, kreg1, vreg0, vreg1;

    f32x16 oT[2] = {};
    float l_acc = 0.f;

    kreg0 = *(const uint4*)(vb + (size_t)sr0 * HD + sc * 8);
    kreg1 = *(const uint4*)(vb + (size_t)sr1 * HD + sc * 8);
    vreg0 = *(const uint4*)(vtb + (size_t)sr0 * NTOK + sc * 8);
    vreg1 = *(const uint4*)(vtb + (size_t)sr1 * NTOK + sc * 8);
    *(uint4*)(&Klds[0][0] + sr0 * 64 + slt) = kreg0;
    *(uint4*)(&Klds[0][0] + sr1 * 64 + slt) = kreg1;
    *(uint4*)(&Vlds[0][0] + sr0 * 64 + slt) = vreg0;
    *(uint4*)(&Vlds[0][0] + sr1 * 64 + slt) = vreg1;
    __syncthreads();

    for (int kt = 0; kt < NTOK / 64; ++kt) {
        const int cur = kt & 1;
        const ushort* Kb = &Klds[cur][0];
        const ushort* Vb = &Vlds[cur][0];

        // T14: issue next tile's global loads early (land during compute)
        if (kt < NTOK / 64 - 1) {
            int kb = (kt + 1) * 64;
            kreg0 = *(const uint4*)(vb + (size_t)(kb + sr0) * HD + sc * 8);
            kreg1 = *(const uint4*)(vb + (size_t)(kb + sr1) * HD + sc * 8);
            vreg0 = *(const uint4*)(vtb + (size_t)sr0 * NTOK + kb + sc * 8);
            vreg1 = *(const uint4*)(vtb + (size_t)sr1 * NTOK + kb + sc * 8);
        }

        // QK^T: both 32-kv groups (chains interleave freely)
        f32x16 st[2] = {};
        #pragma unroll
        for (int ks = 0; ks < 4; ++ks) {
            int so = ((2 * ks + h) ^ (ql & 7)) * 8;
            short8 k0 = *(const short8*)(Kb + ql * 64 + so);
            short8 k1 = *(const short8*)(Kb + (32 + ql) * 64 + so);
            st[0] = mfma32(k0, qB[ks], st[0]);
            st[1] = mfma32(k1, qB[ks], st[1]);
        }

        // per group: exp2 -> sum -> pack -> PV  (group 1's VALU overlaps
        // group 0's PV MFMAs; no setprio fences)
        #pragma unroll
        for (int g = 0; g < 2; ++g) {
            #pragma unroll
            for (int i = 0; i < 16; ++i)
                st[g][i] = __builtin_amdgcn_exp2f(st[g][i]);

            float ts[8];
            #pragma unroll
            for (int i = 0; i < 8; ++i) ts[i] = st[g][i] + st[g][i + 8];
            #pragma unroll
            for (int s = 4; s >= 1; s >>= 1)
                #pragma unroll
                for (int i = 0; i < s; ++i) ts[i] += ts[i + s];
            l_acc += ts[0];

            unsigned pb2[4][2];
            #pragma unroll
            for (int t = 0; t < 4; ++t)
                #pragma unroll
                for (int u = 0; u < 2; ++u)
                    asm("v_cvt_pk_bf16_f32 %0, %1, %2"
                        : "=v"(pb2[t][u])
                        : "v"(st[g][4 * t + 2 * u]), "v"(st[g][4 * t + 2 * u + 1]));

            #pragma unroll
            for (int sp = 0; sp < 2; ++sp) {
                const int s = g * 2 + sp;
                unsigned x0 = pb2[2 * sp][0], y0 = pb2[2 * sp + 1][0];
                unsigned x1 = pb2[2 * sp][1], y1 = pb2[2 * sp + 1][1];
                asm volatile("v_permlane32_swap_b32 %0, %1" : "+v"(x0), "+v"(y0));
                asm volatile("v_permlane32_swap_b32 %0, %1" : "+v"(x1), "+v"(y1));
                union { unsigned u[4]; short8 s8; } pb;
                pb.u[0] = x0; pb.u[1] = x1; pb.u[2] = y0; pb.u[3] = y1;
                int so = ((2 * s + h) ^ (ql & 7)) * 8;
                short8 v0 = *(const short8*)(Vb + ql * 64 + so);
                short8 v1 = *(const short8*)(Vb + (32 + ql) * 64 + so);
                oT[0] = mfma32(v0, pb.s8, oT[0]);
                oT[1] = mfma32(v1, pb.s8, oT[1]);
            }
        }

        __syncthreads();                 // all waves done reading tile kt
        if (kt < NTOK / 64 - 1) {
            *(uint4*)(&Klds[cur ^ 1][0] + sr0 * 64 + slt) = kreg0;
            *(uint4*)(&Klds[cur ^ 1][0] + sr1 * 64 + slt) = kreg1;
            *(uint4*)(&Vlds[cur ^ 1][0] + sr0 * 64 + slt) = vreg0;
            *(uint4*)(&Vlds[cur ^ 1][0] + sr1 * 64 + slt) = vreg1;
            __syncthreads();
        }
    }

    const int b = bh / NH, hh = bh % NH;
    float lsum = l_acc + __shfl_xor(l_acc, 32);
    const float inv = 1.f / lsum;
    int n = q0 + wv * 32 + ql;
    float* orow = out + ((size_t)n * BATCH + b) * DM + hh * HD;
    #pragma unroll
    for (int dm = 0; dm < 2; ++dm)
        #pragma unroll
        for (int t = 0; t < 4; ++t) {
            float4 val = make_float4(oT[dm][4 * t] * inv, oT[dm][4 * t + 1] * inv,
                                     oT[dm][4 * t + 2] * inv, oT[dm][4 * t + 3] * inv);
            *(float4*)(orow + dm * 32 + t * 8 + h * 4) = val;
        }
}

extern "C" void kernel_launch(void* const* d_in, const int* in_sizes, int n_in,
                              void* d_out, int out_size, void* d_ws, size_t ws_size,
                              hipStream_t stream) {
    const float* q = (const float*)d_in[0];   // [1024, 8, 768]
    const float* w = (const float*)d_in[1];   // [768, 768]
    float* out = (float*)d_out;               // [1024, 8, 768]

    const size_t VE = (size_t)NH * BATCH * NTOK * HD;  // 6,291,456
    ushort* vn = (ushort*)d_ws;                        // [96][1024][64] bf16
    ushort* vt = vn + VE;                              // [96][64][1024] bf16

    vproj_mfma_kernel<<<768, 256, 0, stream>>>(q, w, vn, vt);
    attn_kernel<<<NTOK / 128 * BATCH * NH, 256, 0, stream>>>(vn, vt, out);
}

// Round 17
// 89.320 us; speedup vs baseline: 1.0459x; 1.0134x over previous
//
#include <hip/hip_runtime.h>
#include <hip/hip_bf16.h>

#define NH    12
#define HD    64
#define NTOK  1024
#define BATCH 8
#define DM    768

typedef short  short8  __attribute__((ext_vector_type(8)));
typedef float  f32x4   __attribute__((ext_vector_type(4)));
typedef float  f32x16  __attribute__((ext_vector_type(16)));
typedef unsigned short ushort8 __attribute__((ext_vector_type(8)));

// sqrt(0.125 * log2(e)) — pre-scales vn so QK^T yields CS*cos directly
#define SQRT_CS 0.42466056f

__device__ __forceinline__ ushort f2bf(float f) {
    union { float f; unsigned u; } x; x.f = f;
    unsigned r = x.u + 0x7FFF + ((x.u >> 16) & 1);   // RNE
    return (ushort)(r >> 16);
}
__device__ __forceinline__ float bf2f(ushort h) {
    union { unsigned u; float f; } x; x.u = ((unsigned)h) << 16;
    return x.f;
}
__device__ __forceinline__ void gl_lds16f(const float* g, char* l) {
    __builtin_amdgcn_global_load_lds(
        (const __attribute__((address_space(1))) unsigned int*)g,
        (__attribute__((address_space(3))) unsigned int*)l, 16, 0, 0);
}
__device__ __forceinline__ void gl_lds16u(const ushort* g, ushort* l) {
    __builtin_amdgcn_global_load_lds(
        (const __attribute__((address_space(1))) unsigned int*)g,
        (__attribute__((address_space(3))) unsigned int*)l, 16, 0, 0);
}
__device__ __forceinline__ f32x16 mfma32(short8 a, short8 b, f32x16 c) {
    return __builtin_amdgcn_mfma_f32_32x32x16_bf16(a, b, c, 0, 0, 0);
}

// in-register split: 8 fp32 (two uint4) -> hi bf16x8 + lo bf16x8 (RNE, bit-
// identical to the split kernels: hi = bf16(x), lo = bf16(x - hi)).
__device__ __forceinline__ void split8(uint4 c0, uint4 c1,
                                       short8& hi8, short8& lo8) {
    const unsigned xs[8] = {c0.x, c0.y, c0.z, c0.w, c1.x, c1.y, c1.z, c1.w};
    union { unsigned u[4]; short8 s; } H, L;
    #pragma unroll
    for (int j = 0; j < 4; ++j) {
        float a0 = __uint_as_float(xs[2 * j]);
        float a1 = __uint_as_float(xs[2 * j + 1]);
        unsigned hp;
        asm("v_cvt_pk_bf16_f32 %0, %1, %2" : "=v"(hp) : "v"(a0), "v"(a1));
        float l0 = a0 - __uint_as_float(hp << 16);
        float l1 = a1 - __uint_as_float(hp & 0xFFFF0000u);
        unsigned lp;
        asm("v_cvt_pk_bf16_f32 %0, %1, %2" : "=v"(lp) : "v"(l0), "v"(l1));
        H.u[j] = hp; L.u[j] = lp;
    }
    hi8 = H.s; lo8 = L.s;
}

// ---------------------------------------------------------------------------
// split_w: w -> (hi, lo) bf16. Tiny (2.25 MB traffic): removes the 4x-
// redundant per-wave B conversions from the vproj inner loop.
// ---------------------------------------------------------------------------
__global__ __launch_bounds__(256) void split_w_kernel(
    const float* __restrict__ src, ushort* __restrict__ hi, ushort* __restrict__ lo)
{
    int t = blockIdx.x * 256 + threadIdx.x;       // 73728 threads
    if (t >= (DM * DM) / 8) return;
    const float* s = src + (size_t)t * 8;
    float4 x0 = *(const float4*)s, x1 = *(const float4*)(s + 4);
    float xs[8] = {x0.x, x0.y, x0.z, x0.w, x1.x, x1.y, x1.z, x1.w};
    ushort8 h8, l8;
    #pragma unroll
    for (int j = 0; j < 8; ++j) {
        ushort h = f2bf(xs[j]);
        h8[j] = h;
        l8[j] = f2bf(xs[j] - bf2f(h));
    }
    size_t o = (size_t)t * 8;
    *(ushort8*)(hi + o) = h8;
    *(ushort8*)(lo + o) = l8;
}

// ---------------------------------------------------------------------------
// vproj (hybrid split): C = Ah.Bh + Ah.Bl + Al.Bh (fp32 accum).
// A (q) staged fp32 + split IN-REGISTER (per-wave-unique, 4 split8/kt);
// B (w) staged from PRE-SPLIT bf16 hi/lo (removes the 4x-redundant 8
// split8/kt/wave that made round-16's VALUBusy 41%).
// 128x64 tile (one head), BK=64, 4 waves of 32 rows. A fp32 rows as two
// 128B-row subtiles (even/odd k-half), B bf16 [64][64] rows; both with the
// ^(r&7) chunk swizzle (0-conflict verified). Grid 768, XCD-pinned.
// Epilogue: Ct [128][68] f32 bounce -> row norm -> vn (xSQRT_CS) + vt.
// ---------------------------------------------------------------------------
__global__ __launch_bounds__(256) void vproj_mfma_kernel(
    const float* __restrict__ qf,
    const ushort* __restrict__ wh, const ushort* __restrict__ wl,
    ushort* __restrict__ vn, ushort* __restrict__ vt)
{
    __shared__ __align__(16) char smem[49152];   // 48 KB
    char*   Ae = smem;               // A k-half [0,32): [128][128B] swizzled
    char*   Ao = smem + 16384;       // A k-half [32,64)
    ushort* Bh = (ushort*)(smem + 32768);   // [64][64] bf16 swizzled
    ushort* Bl = (ushort*)(smem + 40960);

    const int bid = blockIdx.x;                  // 0..767
    const int xcd = bid & 7, idx = bid >> 3;     // idx 0..95
    const int mbl = idx & 7, hh = idx >> 3;      // hh 0..11 (head)
    const int mb  = xcd * 8 + mbl;               // 0..63 row-panel
    const int b   = mb >> 3;
    const int nr0 = (mb & 7) * 128;
    const int n0  = hh * 64;

    const int tid = threadIdx.x, wv = tid >> 6, l = tid & 63;
    const int ln  = l & 31, half = l >> 5;

    f32x16 acc[2] = {};

    for (int kt = 0; kt < 12; ++kt) {
        __syncthreads();                          // prev ds_reads done
        if (wv < 2) {                             // A: fp32, 16 instr/wave
            char* dstT = wv ? Ao : Ae;
            const int kofs = kt * 64 + wv * 32;
            #pragma unroll
            for (int p = 0; p < 16; ++p) {
                int chunk = p * 64 + l;
                int r = chunk >> 3, c = chunk & 7;
                int csrc = c ^ (r & 7);           // inverse-swizzled source
                gl_lds16f(qf + ((size_t)((nr0 + r) * 8 + b)) * 768 + kofs + csrc * 4,
                          dstT + p * 1024);
            }
        } else {                                  // B: pre-split bf16, 8 instr
            const ushort* gsrc = (wv == 3) ? wl : wh;
            ushort* dstT = (wv == 3) ? Bl : Bh;
            #pragma unroll
            for (int p = 0; p < 8; ++p) {
                int chunk = p * 64 + l;
                int r = chunk >> 3, c = chunk & 7;
                int csrc = c ^ (r & 7);
                gl_lds16u(gsrc + (size_t)(n0 + r) * 768 + kt * 64 + csrc * 8,
                          dstT + p * 512);
            }
        }
        __syncthreads();                          // vmcnt(0) drained here

        #pragma unroll
        for (int ks = 0; ks < 4; ++ks) {
            const int cc  = ks * 2 + half;        // bf16 k-chunk 0..7
            const int cc2 = (cc & 3) * 2;         // fp32 16B-chunk pair base
            const int ra  = wv * 32 + ln;
            const char* At = (cc < 4) ? Ae : Ao;
            uint4 a0 = *(const uint4*)(At + ra * 128 + ((cc2 ^ (ra & 7)) * 16));
            uint4 a1 = *(const uint4*)(At + ra * 128 + (((cc2 + 1) ^ (ra & 7)) * 16));
            short8 a_h, a_l;
            split8(a0, a1, a_h, a_l);
            short8 b_h[2], b_l[2];
            #pragma unroll
            for (int ni = 0; ni < 2; ++ni) {
                int rb = ni * 32 + ln;
                int sb = (cc ^ (rb & 7)) * 8;
                b_h[ni] = *(const short8*)(Bh + rb * 64 + sb);
                b_l[ni] = *(const short8*)(Bl + rb * 64 + sb);
            }
            #pragma unroll
            for (int ni = 0; ni < 2; ++ni) {
                acc[ni] = mfma32(a_h, b_h[ni], acc[ni]);
                acc[ni] = mfma32(a_h, b_l[ni], acc[ni]);
                acc[ni] = mfma32(a_l, b_h[ni], acc[ni]);
            }
        }
    }

    // ---- epilogue: C tile -> LDS [128][68] f32, norms, vn + vt ----
    __syncthreads();
    float* Ct = (float*)smem;                     // 128*68*4 = 34816 B
    #pragma unroll
    for (int ni = 0; ni < 2; ++ni)
        #pragma unroll
        for (int i = 0; i < 16; ++i) {
            int row = wv * 32 + (i & 3) + 8 * (i >> 2) + 4 * half;
            Ct[row * 68 + ni * 32 + ln] = acc[ni][i];
        }
    __syncthreads();

    const int bhn = b * NH + hh;
    {   // vn: thread t -> row t>>1, 32-col part t&1 (pair-reduce via shfl)
        int r = tid >> 1, part = tid & 1;
        const float* src = Ct + r * 68 + part * 32;
        float ss = 0.f;
        #pragma unroll
        for (int j = 0; j < 8; ++j) {
            float4 v4 = *(const float4*)(src + j * 4);
            ss += v4.x * v4.x + v4.y * v4.y + v4.z * v4.z + v4.w * v4.w;
        }
        ss += __shfl_xor(ss, 1);
        float rn = rsqrtf(ss) * SQRT_CS;          // fold softmax scale into vn
        ushort* dst = vn + ((size_t)bhn * NTOK + nr0 + r) * HD + part * 32;
        #pragma unroll
        for (int q8 = 0; q8 < 4; ++q8) {
            float4 u0 = *(const float4*)(src + q8 * 8);
            float4 u1 = *(const float4*)(src + q8 * 8 + 4);
            ushort8 o;
            o[0] = f2bf(u0.x * rn); o[1] = f2bf(u0.y * rn);
            o[2] = f2bf(u0.z * rn); o[3] = f2bf(u0.w * rn);
            o[4] = f2bf(u1.x * rn); o[5] = f2bf(u1.y * rn);
            o[6] = f2bf(u1.z * rn); o[7] = f2bf(u1.w * rn);
            *(ushort8*)(dst + q8 * 8) = o;
        }
    }
    {   // vt: thread t -> col d = t&63, 32-row segment seg = t>>6
        int d = tid & 63, seg = tid >> 6;
        ushort* dst = vt + ((size_t)bhn * HD + d) * NTOK + nr0 + seg * 32;
        #pragma unroll
        for (int q8 = 0; q8 < 4; ++q8) {
            ushort8 o;
            #pragma unroll
            for (int j = 0; j < 8; ++j)
                o[j] = f2bf(Ct[(seg * 32 + q8 * 8 + j) * 68 + d]);
            *(ushort8*)(dst + q8 * 8) = o;
        }
    }
}

// ---------------------------------------------------------------------------
// Fallback vproj (round-16 all-in-register version) if ws can't hold wh/wl.
// ---------------------------------------------------------------------------
__global__ __launch_bounds__(256) void vproj_mfma_irs_kernel(
    const float* __restrict__ qf, const float* __restrict__ wf,
    ushort* __restrict__ vn, ushort* __restrict__ vt)
{
    __shared__ __align__(16) char smem[49152];
    char* Ae = smem;
    char* Ao = smem + 16384;
    char* Be = smem + 32768;
    char* Bo = smem + 40960;

    const int bid = blockIdx.x;
    const int xcd = bid & 7, idx = bid >> 3;
    const int mbl = idx & 7, hh = idx >> 3;
    const int mb  = xcd * 8 + mbl;
    const int b   = mb >> 3;
    const int nr0 = (mb & 7) * 128;
    const int n0  = hh * 64;

    const int tid = threadIdx.x, wv = tid >> 6, l = tid & 63;
    const int ln  = l & 31, half = l >> 5;

    f32x16 acc[2] = {};

    for (int kt = 0; kt < 12; ++kt) {
        __syncthreads();
        if (wv < 2) {
            char* dstT = wv ? Ao : Ae;
            const int kofs = kt * 64 + wv * 32;
            #pragma unroll
            for (int p = 0; p < 16; ++p) {
                int chunk = p * 64 + l;
                int r = chunk >> 3, c = chunk & 7;
                int csrc = c ^ (r & 7);
                gl_lds16f(qf + ((size_t)((nr0 + r) * 8 + b)) * 768 + kofs + csrc * 4,
                          dstT + p * 1024);
            }
        } else {
            char* dstT = (wv == 3) ? Bo : Be;
            const int kofs = kt * 64 + (wv == 3 ? 32 : 0);
            #pragma unroll
            for (int p = 0; p < 8; ++p) {
                int chunk = p * 64 + l;
                int r = chunk >> 3, c = chunk & 7;
                int csrc = c ^ (r & 7);
                gl_lds16f(wf + (size_t)(n0 + r) * 768 + kofs + csrc * 4,
                          dstT + p * 1024);
            }
        }
        __syncthreads();

        #pragma unroll
        for (int ks = 0; ks < 4; ++ks) {
            const int cc  = ks * 2 + half;
            const int cc2 = (cc & 3) * 2;
            const int ra  = wv * 32 + ln;
            const char* At = (cc < 4) ? Ae : Ao;
            uint4 a0 = *(const uint4*)(At + ra * 128 + ((cc2 ^ (ra & 7)) * 16));
            uint4 a1 = *(const uint4*)(At + ra * 128 + (((cc2 + 1) ^ (ra & 7)) * 16));
            short8 a_h, a_l;
            split8(a0, a1, a_h, a_l);
            short8 b_h[2], b_l[2];
            const char* Bt = (cc < 4) ? Be : Bo;
            #pragma unroll
            for (int ni = 0; ni < 2; ++ni) {
                int rb = ni * 32 + ln;
                uint4 b0 = *(const uint4*)(Bt + rb * 128 + ((cc2 ^ (rb & 7)) * 16));
                uint4 b1 = *(const uint4*)(Bt + rb * 128 + (((cc2 + 1) ^ (rb & 7)) * 16));
                split8(b0, b1, b_h[ni], b_l[ni]);
            }
            #pragma unroll
            for (int ni = 0; ni < 2; ++ni) {
                acc[ni] = mfma32(a_h, b_h[ni], acc[ni]);
                acc[ni] = mfma32(a_h, b_l[ni], acc[ni]);
                acc[ni] = mfma32(a_l, b_h[ni], acc[ni]);
            }
        }
    }

    __syncthreads();
    float* Ct = (float*)smem;
    #pragma unroll
    for (int ni = 0; ni < 2; ++ni)
        #pragma unroll
        for (int i = 0; i < 16; ++i) {
            int row = wv * 32 + (i & 3) + 8 * (i >> 2) + 4 * half;
            Ct[row * 68 + ni * 32 + ln] = acc[ni][i];
        }
    __syncthreads();

    const int bhn = b * NH + hh;
    {
        int r = tid >> 1, part = tid & 1;
        const float* src = Ct + r * 68 + part * 32;
        float ss = 0.f;
        #pragma unroll
        for (int j = 0; j < 8; ++j) {
            float4 v4 = *(const float4*)(src + j * 4);
            ss += v4.x * v4.x + v4.y * v4.y + v4.z * v4.z + v4.w * v4.w;
        }
        ss += __shfl_xor(ss, 1);
        float rn = rsqrtf(ss) * SQRT_CS;
        ushort* dst = vn + ((size_t)bhn * NTOK + nr0 + r) * HD + part * 32;
        #pragma unroll
        for (int q8 = 0; q8 < 4; ++q8) {
            float4 u0 = *(const float4*)(src + q8 * 8);
            float4 u1 = *(const float4*)(src + q8 * 8 + 4);
            ushort8 o;
            o[0] = f2bf(u0.x * rn); o[1] = f2bf(u0.y * rn);
            o[2] = f2bf(u0.z * rn); o[3] = f2bf(u0.w * rn);
            o[4] = f2bf(u1.x * rn); o[5] = f2bf(u1.y * rn);
            o[6] = f2bf(u1.z * rn); o[7] = f2bf(u1.w * rn);
            *(ushort8*)(dst + q8 * 8) = o;
        }
    }
    {
        int d = tid & 63, seg = tid >> 6;
        ushort* dst = vt + ((size_t)bhn * HD + d) * NTOK + nr0 + seg * 32;
        #pragma unroll
        for (int q8 = 0; q8 < 4; ++q8) {
            ushort8 o;
            #pragma unroll
            for (int j = 0; j < 8; ++j)
                o[j] = f2bf(Ct[(seg * 32 + q8 * 8 + j) * 68 + d]);
            *(ushort8*)(dst + q8 * 8) = o;
        }
    }
}

// ---------------------------------------------------------------------------
// Kernel 2: flash attention, round-12 group-pipelined version (unchanged).
// ---------------------------------------------------------------------------
__global__ __launch_bounds__(256) void attn_kernel(
    const ushort* __restrict__ vn, const ushort* __restrict__ vt,
    float* __restrict__ out)
{
    __shared__ __align__(16) ushort Klds[2][64 * 64];   // [kv][d], swizzled
    __shared__ __align__(16) ushort Vlds[2][64 * 64];   // [d][kv], swizzled
    const int sblk = blockIdx.x;                 // 0..767
    const int tt   = sblk >> 3;
    const int bh   = (sblk & 7) + 8 * (tt >> 3); // XCD(bid%8) == bh%8
    const int q0   = (tt & 7) * 128;
    const int tid = threadIdx.x;
    const int wv  = tid >> 6;
    const int l   = tid & 63;
    const int ql  = l & 31;          // q column (one q-row per lane)
    const int h   = l >> 5;          // half

    const ushort* vb  = vn + (size_t)bh * NTOK * HD;
    const ushort* vtb = vt + (size_t)bh * HD * NTOK;

    short8 qB[4];
    {
        int qrow = q0 + wv * 32 + ql;
        #pragma unroll
        for (int ks = 0; ks < 4; ++ks)
            qB[ks] = *(const short8*)(vb + (size_t)qrow * HD + ks * 16 + h * 8);
    }

    const int sr0 = tid >> 3, sr1 = sr0 + 32;
    const int sc  = tid & 7;
    const int slt = (sc ^ (sr0 & 7)) * 8;        // sr1&7 == sr0&7
    uint4 kreg0, kreg1, vreg0, vreg1;

    f32x16 oT[2] = {};
    float l_acc = 0.f;

    kreg0 = *(const uint4*)(vb + (size_t)sr0 * HD + sc * 8);
    kreg1 = *(const uint4*)(vb + (size_t)sr1 * HD + sc * 8);
    vreg0 = *(const uint4*)(vtb + (size_t)sr0 * NTOK + sc * 8);
    vreg1 = *(const uint4*)(vtb + (size_t)sr1 * NTOK + sc * 8);
    *(uint4*)(&Klds[0][0] + sr0 * 64 + slt) = kreg0;
    *(uint4*)(&Klds[0][0] + sr1 * 64 + slt) = kreg1;
    *(uint4*)(&Vlds[0][0] + sr0 * 64 + slt) = vreg0;
    *(uint4*)(&Vlds[0][0] + sr1 * 64 + slt) = vreg1;
    __syncthreads();

    for (int kt = 0; kt < NTOK / 64; ++kt) {
        const int cur = kt & 1;
        const ushort* Kb = &Klds[cur][0];
        const ushort* Vb = &Vlds[cur][0];

        // T14: issue next tile's global loads early (land during compute)
        if (kt < NTOK / 64 - 1) {
            int kb = (kt + 1) * 64;
            kreg0 = *(const uint4*)(vb + (size_t)(kb + sr0) * HD + sc * 8);
            kreg1 = *(const uint4*)(vb + (size_t)(kb + sr1) * HD + sc * 8);
            vreg0 = *(const uint4*)(vtb + (size_t)sr0 * NTOK + kb + sc * 8);
            vreg1 = *(const uint4*)(vtb + (size_t)sr1 * NTOK + kb + sc * 8);
        }

        // QK^T: both 32-kv groups (chains interleave freely)
        f32x16 st[2] = {};
        #pragma unroll
        for (int ks = 0; ks < 4; ++ks) {
            int so = ((2 * ks + h) ^ (ql & 7)) * 8;
            short8 k0 = *(const short8*)(Kb + ql * 64 + so);
            short8 k1 = *(const short8*)(Kb + (32 + ql) * 64 + so);
            st[0] = mfma32(k0, qB[ks], st[0]);
            st[1] = mfma32(k1, qB[ks], st[1]);
        }

        // per group: exp2 -> sum -> pack -> PV  (group 1's VALU overlaps
        // group 0's PV MFMAs; no setprio fences)
        #pragma unroll
        for (int g = 0; g < 2; ++g) {
            #pragma unroll
            for (int i = 0; i < 16; ++i)
                st[g][i] = __builtin_amdgcn_exp2f(st[g][i]);

            float ts[8];
            #pragma unroll
            for (int i = 0; i < 8; ++i) ts[i] = st[g][i] + st[g][i + 8];
            #pragma unroll
            for (int s = 4; s >= 1; s >>= 1)
                #pragma unroll
                for (int i = 0; i < s; ++i) ts[i] += ts[i + s];
            l_acc += ts[0];

            unsigned pb2[4][2];
            #pragma unroll
            for (int t = 0; t < 4; ++t)
                #pragma unroll
                for (int u = 0; u < 2; ++u)
                    asm("v_cvt_pk_bf16_f32 %0, %1, %2"
                        : "=v"(pb2[t][u])
                        : "v"(st[g][4 * t + 2 * u]), "v"(st[g][4 * t + 2 * u + 1]));

            #pragma unroll
            for (int sp = 0; sp < 2; ++sp) {
                const int s = g * 2 + sp;
                unsigned x0 = pb2[2 * sp][0], y0 = pb2[2 * sp + 1][0];
                unsigned x1 = pb2[2 * sp][1], y1 = pb2[2 * sp + 1][1];
                asm volatile("v_permlane32_swap_b32 %0, %1" : "+v"(x0), "+v"(y0));
                asm volatile("v_permlane32_swap_b32 %0, %1" : "+v"(x1), "+v"(y1));
                union { unsigned u[4]; short8 s8; } pb;
                pb.u[0] = x0; pb.u[1] = x1; pb.u[2] = y0; pb.u[3] = y1;
                int so = ((2 * s + h) ^ (ql & 7)) * 8;
                short8 v0 = *(const short8*)(Vb + ql * 64 + so);
                short8 v1 = *(const short8*)(Vb + (32 + ql) * 64 + so);
                oT[0] = mfma32(v0, pb.s8, oT[0]);
                oT[1] = mfma32(v1, pb.s8, oT[1]);
            }
        }

        __syncthreads();                 // all waves done reading tile kt
        if (kt < NTOK / 64 - 1) {
            *(uint4*)(&Klds[cur ^ 1][0] + sr0 * 64 + slt) = kreg0;
            *(uint4*)(&Klds[cur ^ 1][0] + sr1 * 64 + slt) = kreg1;
            *(uint4*)(&Vlds[cur ^ 1][0] + sr0 * 64 + slt) = vreg0;
            *(uint4*)(&Vlds[cur ^ 1][0] + sr1 * 64 + slt) = vreg1;
            __syncthreads();
        }
    }

    const int b = bh / NH, hh = bh % NH;
    float lsum = l_acc + __shfl_xor(l_acc, 32);
    const float inv = 1.f / lsum;
    int n = q0 + wv * 32 + ql;
    float* orow = out + ((size_t)n * BATCH + b) * DM + hh * HD;
    #pragma unroll
    for (int dm = 0; dm < 2; ++dm)
        #pragma unroll
        for (int t = 0; t < 4; ++t) {
            float4 val = make_float4(oT[dm][4 * t] * inv, oT[dm][4 * t + 1] * inv,
                                     oT[dm][4 * t + 2] * inv, oT[dm][4 * t + 3] * inv);
            *(float4*)(orow + dm * 32 + t * 8 + h * 4) = val;
        }
}

extern "C" void kernel_launch(void* const* d_in, const int* in_sizes, int n_in,
                              void* d_out, int out_size, void* d_ws, size_t ws_size,
                              hipStream_t stream) {
    const float* q = (const float*)d_in[0];   // [1024, 8, 768]
    const float* w = (const float*)d_in[1];   // [768, 768]
    float* out = (float*)d_out;               // [1024, 8, 768]

    const size_t VE = (size_t)NH * BATCH * NTOK * HD;  // 6,291,456
    const size_t WE = (size_t)DM * DM;                 //   589,824
    ushort* vn = (ushort*)d_ws;                        // [96][1024][64] bf16
    ushort* vt = vn + VE;                              // [96][64][1024] bf16
    ushort* wh = vt + VE;
    ushort* wl = wh + WE;
    size_t need = (2 * VE + 2 * WE) * sizeof(ushort);

    if (ws_size >= need) {
        split_w_kernel<<<(WE / 8 + 255) / 256, 256, 0, stream>>>(w, wh, wl);
        vproj_mfma_kernel<<<768, 256, 0, stream>>>(q, wh, wl, vn, vt);
    } else {
        vproj_mfma_irs_kernel<<<768, 256, 0, stream>>>(q, w, vn, vt);
    }
    attn_kernel<<<NTOK / 128 * BATCH * NH, 256, 0, stream>>>(vn, vt, out);
}